// Round 4
// baseline (150.022 us; speedup 1.0000x reference)
//
#include <hip/hip_runtime.h>
#include <math.h>

#define HW   512
#define IMG  (512 * 512)
#define NB   64
#define BLOCK 256
#define WAVES_PER_BLOCK (BLOCK / 64)
#define TOTAL_ROWS (NB * HW)                       // 32768 waves, one per row
#define NBLOCKS    (TOTAL_ROWS / WAVES_PER_BLOCK)  // 8192

__global__ __launch_bounds__(BLOCK) void eik_main(const float* __restrict__ pred,
                                                  const float* __restrict__ reach,
                                                  float* __restrict__ partials) {
    const int lane = threadIdx.x & 63;
    const int w    = blockIdx.x * WAVES_PER_BLOCK + (threadIdx.x >> 6);
    const int y    = w & (HW - 1);
    const int b    = w >> 9;

    const int ym = (y > 0)      ? y - 1 : 0;
    const int yp = (y < HW - 1) ? y + 1 : HW - 1;

    const float* base = pred + (size_t)b * IMG;
    const float* pm = base + (size_t)ym * HW + (lane << 3);
    const float* p0 = base + (size_t)y  * HW + (lane << 3);
    const float* pp = base + (size_t)yp * HW + (lane << 3);
    const float* rp = reach + (size_t)b * IMG + (size_t)y * HW + (lane << 3);

    // 8 independent 16B loads — all issued before any use
    const float4 m0 = *(const float4*)pm;
    const float4 m1 = *(const float4*)(pm + 4);
    const float4 c0 = *(const float4*)p0;
    const float4 c1 = *(const float4*)(p0 + 4);
    const float4 q0 = *(const float4*)pp;
    const float4 q1 = *(const float4*)(pp + 4);
    const float4 r0 = *(const float4*)rp;
    const float4 r1 = *(const float4*)(rp + 4);

    const float am[8] = {m0.x, m0.y, m0.z, m0.w, m1.x, m1.y, m1.z, m1.w};
    const float a0[8] = {c0.x, c0.y, c0.z, c0.w, c1.x, c1.y, c1.z, c1.w};
    const float ap[8] = {q0.x, q0.y, q0.z, q0.w, q1.x, q1.y, q1.z, q1.w};
    const float rv[8] = {r0.x, r0.y, r0.z, r0.w, r1.x, r1.y, r1.z, r1.w};

    // separable Sobel: S = vertical [1,2,1] sum, D = vertical [-1,0,1] diff
    float s[8], d[8];
#pragma unroll
    for (int i = 0; i < 8; ++i) {
        s[i] = am[i] + 2.0f * a0[i] + ap[i];
        d[i] = ap[i] - am[i];
    }

    // x-halo via in-wave shuffle (edge replicate at image borders)
    float sl = __shfl_up(s[7], 1, 64);
    float dl = __shfl_up(d[7], 1, 64);
    float sr = __shfl_down(s[0], 1, 64);
    float dr = __shfl_down(d[0], 1, 64);
    if (lane == 0)  { sl = s[0]; dl = d[0]; }
    if (lane == 63) { sr = s[7]; dr = d[7]; }

    const float S[10] = {sl, s[0], s[1], s[2], s[3], s[4], s[5], s[6], s[7], sr};
    const float D[10] = {dl, d[0], d[1], d[2], d[3], d[4], d[5], d[6], d[7], dr};

    float vsum = 0.0f, csum = 0.0f;
#pragma unroll
    for (int i = 0; i < 8; ++i) {
        const float gx = (S[i+2] - S[i]) * 0.125f;
        const float gy = (D[i] + 2.0f * D[i+1] + D[i+2]) * 0.125f;
        const float mag  = sqrtf(gx * gx + gy * gy + 1e-8f);
        const float viol = fabsf(mag - 1.0f);
        const bool  m    = rv[i] > 0.5f;
        vsum += m ? viol : 0.0f;
        csum += m ? 1.0f : 0.0f;
    }

    // wave-64 reduction
#pragma unroll
    for (int off = 32; off > 0; off >>= 1) {
        vsum += __shfl_down(vsum, off, 64);
        csum += __shfl_down(csum, off, 64);
    }

    __shared__ float sv[WAVES_PER_BLOCK];
    __shared__ float sc[WAVES_PER_BLOCK];
    const int wid = threadIdx.x >> 6;
    if (lane == 0) { sv[wid] = vsum; sc[wid] = csum; }
    __syncthreads();
    if (threadIdx.x == 0) {
        partials[2 * blockIdx.x]     = sv[0] + sv[1] + sv[2] + sv[3];
        partials[2 * blockIdx.x + 1] = sc[0] + sc[1] + sc[2] + sc[3];
    }
}

__global__ __launch_bounds__(BLOCK) void eik_finalize(const float* __restrict__ partials,
                                                      float* __restrict__ out) {
    float v = 0.0f, c = 0.0f;
    for (int i = threadIdx.x; i < NBLOCKS; i += BLOCK) {
        v += partials[2 * i];
        c += partials[2 * i + 1];
    }
#pragma unroll
    for (int off = 32; off > 0; off >>= 1) {
        v += __shfl_down(v, off, 64);
        c += __shfl_down(c, off, 64);
    }
    __shared__ float sv[WAVES_PER_BLOCK];
    __shared__ float sc[WAVES_PER_BLOCK];
    const int lane = threadIdx.x & 63;
    const int wid  = threadIdx.x >> 6;
    if (lane == 0) { sv[wid] = v; sc[wid] = c; }
    __syncthreads();
    if (threadIdx.x == 0) {
        const float vt = sv[0] + sv[1] + sv[2] + sv[3];
        const float ct = sc[0] + sc[1] + sc[2] + sc[3];
        out[0] = vt / fmaxf(ct, 1.0f);
    }
}

extern "C" void kernel_launch(void* const* d_in, const int* in_sizes, int n_in,
                              void* d_out, int out_size, void* d_ws, size_t ws_size,
                              hipStream_t stream) {
    const float* pred  = (const float*)d_in[0];
    const float* reach = (const float*)d_in[1];
    float* out = (float*)d_out;
    float* ws  = (float*)d_ws;

    eik_main<<<NBLOCKS, BLOCK, 0, stream>>>(pred, reach, ws);
    eik_finalize<<<1, BLOCK, 0, stream>>>(ws, out);
}

// Round 5
// 146.730 us; speedup vs baseline: 1.0224x; 1.0224x over previous
//
#include <hip/hip_runtime.h>
#include <math.h>

#define HW   512
#define IMG  (512 * 512)
#define NB   64
#define T    4
#define BLOCK 256
#define WAVES_PER_BLOCK (BLOCK / 64)
#define WAVES_PER_IMG (HW / T)                      // 128
#define TOTAL_WAVES (NB * WAVES_PER_IMG)            // 8192
#define NBLOCKS     (TOTAL_WAVES / WAVES_PER_BLOCK) // 2048

__device__ __forceinline__ void unpack8(const float4& q0, const float4& q1, float* a) {
    a[0] = q0.x; a[1] = q0.y; a[2] = q0.z; a[3] = q0.w;
    a[4] = q1.x; a[5] = q1.y; a[6] = q1.z; a[7] = q1.w;
}

__global__ __launch_bounds__(BLOCK) void eik_main(const float* __restrict__ pred,
                                                  const float* __restrict__ reach,
                                                  float* __restrict__ partials) {
    const int lane = threadIdx.x & 63;
    const int w    = blockIdx.x * WAVES_PER_BLOCK + (threadIdx.x >> 6);
    const int y0   = (w & (WAVES_PER_IMG - 1)) * T;
    const int b    = w >> 7;
    const int xo   = lane << 3;

    const float* base = pred + (size_t)b * IMG;

    // 6 pred rows (y0-1 .. y0+4, edge-clamped) + 4 reach rows:
    // 20 independent 16B loads issued before any use.
    float4 P[6][2];
#pragma unroll
    for (int j = 0; j < 6; ++j) {
        int r = y0 - 1 + j;
        r = r < 0 ? 0 : (r > HW - 1 ? HW - 1 : r);
        const float* p = base + (size_t)r * HW + xo;
        P[j][0] = *(const float4*)p;
        P[j][1] = *(const float4*)(p + 4);
    }
    float4 R[T][2];
    const float* rbase = reach + (size_t)b * IMG + (size_t)y0 * HW + xo;
#pragma unroll
    for (int t = 0; t < T; ++t) {
        R[t][0] = *(const float4*)(rbase + (size_t)t * HW);
        R[t][1] = *(const float4*)(rbase + (size_t)t * HW + 4);
    }

    float vsum = 0.0f, csum = 0.0f;

#pragma unroll
    for (int t = 0; t < T; ++t) {
        float am[8], a0[8], ap[8], rv[8];
        unpack8(P[t][0],     P[t][1],     am);
        unpack8(P[t + 1][0], P[t + 1][1], a0);
        unpack8(P[t + 2][0], P[t + 2][1], ap);
        unpack8(R[t][0],     R[t][1],     rv);

        // separable Sobel: S = vertical [1,2,1], D = vertical [-1,0,1]
        float s[8], d[8];
#pragma unroll
        for (int i = 0; i < 8; ++i) {
            s[i] = am[i] + 2.0f * a0[i] + ap[i];
            d[i] = ap[i] - am[i];
        }

        float sl = __shfl_up(s[7], 1, 64);
        float dl = __shfl_up(d[7], 1, 64);
        float sr = __shfl_down(s[0], 1, 64);
        float dr = __shfl_down(d[0], 1, 64);
        if (lane == 0)  { sl = s[0]; dl = d[0]; }
        if (lane == 63) { sr = s[7]; dr = d[7]; }

        const float S[10] = {sl, s[0], s[1], s[2], s[3], s[4], s[5], s[6], s[7], sr};
        const float D[10] = {dl, d[0], d[1], d[2], d[3], d[4], d[5], d[6], d[7], dr};

#pragma unroll
        for (int i = 0; i < 8; ++i) {
            const float gx = (S[i+2] - S[i]) * 0.125f;
            const float gy = (D[i] + 2.0f * D[i+1] + D[i+2]) * 0.125f;
            const float mag  = __builtin_amdgcn_sqrtf(gx * gx + gy * gy + 1e-8f);
            const float viol = fabsf(mag - 1.0f);
            const bool  m    = rv[i] > 0.5f;
            vsum += m ? viol : 0.0f;
            csum += m ? 1.0f : 0.0f;
        }
    }

    // wave-64 reduction (amortized over T rows)
#pragma unroll
    for (int off = 32; off > 0; off >>= 1) {
        vsum += __shfl_down(vsum, off, 64);
        csum += __shfl_down(csum, off, 64);
    }

    __shared__ float sv[WAVES_PER_BLOCK];
    __shared__ float sc[WAVES_PER_BLOCK];
    const int wid = threadIdx.x >> 6;
    if (lane == 0) { sv[wid] = vsum; sc[wid] = csum; }
    __syncthreads();
    if (threadIdx.x == 0) {
        partials[2 * blockIdx.x]     = sv[0] + sv[1] + sv[2] + sv[3];
        partials[2 * blockIdx.x + 1] = sc[0] + sc[1] + sc[2] + sc[3];
    }
}

__global__ __launch_bounds__(BLOCK) void eik_finalize(const float* __restrict__ partials,
                                                      float* __restrict__ out) {
    float v = 0.0f, c = 0.0f;
    for (int i = threadIdx.x; i < NBLOCKS; i += BLOCK) {
        v += partials[2 * i];
        c += partials[2 * i + 1];
    }
#pragma unroll
    for (int off = 32; off > 0; off >>= 1) {
        v += __shfl_down(v, off, 64);
        c += __shfl_down(c, off, 64);
    }
    __shared__ float sv[WAVES_PER_BLOCK];
    __shared__ float sc[WAVES_PER_BLOCK];
    const int lane = threadIdx.x & 63;
    const int wid  = threadIdx.x >> 6;
    if (lane == 0) { sv[wid] = v; sc[wid] = c; }
    __syncthreads();
    if (threadIdx.x == 0) {
        const float vt = sv[0] + sv[1] + sv[2] + sv[3];
        const float ct = sc[0] + sc[1] + sc[2] + sc[3];
        out[0] = vt / fmaxf(ct, 1.0f);
    }
}

extern "C" void kernel_launch(void* const* d_in, const int* in_sizes, int n_in,
                              void* d_out, int out_size, void* d_ws, size_t ws_size,
                              hipStream_t stream) {
    const float* pred  = (const float*)d_in[0];
    const float* reach = (const float*)d_in[1];
    float* out = (float*)d_out;
    float* ws  = (float*)d_ws;

    eik_main<<<NBLOCKS, BLOCK, 0, stream>>>(pred, reach, ws);
    eik_finalize<<<1, BLOCK, 0, stream>>>(ws, out);
}